// Round 17
// baseline (70.775 us; speedup 1.0000x reference)
//
#include <hip/hip_runtime.h>
#include <math.h>

// LinearGating: B=4,S=4096,D=2048,E=64,K=2 -> N=16384 rows
// out (flat f32): [weights N*64][indices N*2 (as float)][logits N*64][probs N*64]
//
// fp16 split-3 MFMA GEMM: C[N x 128] = X[N x 2048] @ [Wg|Wn]
//   x = h + d, w = H + D;  acc1 += h*H ; acc2 += h*(D*2^6) + (d*2^6)*H
// R17: GRID SPLIT-K. Phase-1 = R15's unpinned pipeline over a K-slice of
// 2048/NSP (NSP=4 -> 8 segs/block, grid 512x4 = 16384 waves, ~75% occupancy
// vs the 50% structural cap of all single-pass variants). fp32 partials to
// d_ws. Phase-2 = reduce 4 partials + noise + top-2 + softmax (R4-verified
// 64-row epilogue). Fallback NSP=2 if ws_size is small.

typedef _Float16 f16;
typedef f16  f16x4  __attribute__((ext_vector_type(4)));
typedef f16  f16x8  __attribute__((ext_vector_type(8)));
typedef float f32x16 __attribute__((ext_vector_type(16)));

constexpr int NROWS = 16384;
constexpr int DDIM  = 2048;
constexpr int NE    = 64;
constexpr int BM    = 32;
constexpr float NSCALE = 1.0f / 4096.0f;

__device__ __forceinline__ int a_off(int buf, int h, int s, int v) {
    return (((buf * 2 + h) * 2 + s) * 2 + v) * 1024;
}

__device__ __forceinline__ float softplus_f(float x) {
    return fmaxf(x, 0.0f) + log1pf(expf(-fabsf(x)));
}

// ---------------- W prep: fragment-ordered fp16 {H, D*2^6} ----------------
__global__ __launch_bounds__(256) void wprep_kernel(
    const float* __restrict__ Wg, const float* __restrict__ Wn,
    f16* __restrict__ ws)
{
    int t = blockIdx.x * 256 + threadIdx.x;    // 0..32767
    int S = t >> 8;
    int f = (t >> 6) & 3;
    int l = t & 63;
    int k0  = S * 16 + (l >> 5) * 8;
    int col = f * 32 + (l & 31);
    const float* src = (col < NE) ? (Wg + col) : (Wn + col - NE);
    f16x8 hp, lp;
    #pragma unroll
    for (int j = 0; j < 8; ++j) {
        float w  = src[(size_t)(k0 + j) * NE];
        f16 h    = (f16)w;
        float hf = (float)h;
        hp[j] = h;
        lp[j] = (f16)((w - hf) * 64.0f);
    }
    size_t base = (size_t)(S * 4 + f) * 1024;   // f16 units
    *(f16x8*)(ws + base + l * 8)       = hp;
    *(f16x8*)(ws + base + 512 + l * 8) = lp;
}

// ---------------- phase 1: split-K GEMM -> fp32 partials ----------------
template<int NSP>
__global__ __launch_bounds__(512, 4) void gemm_phase1(
    const float* __restrict__ x, const f16* __restrict__ wfrag,
    float* __restrict__ part)
{
    constexpr int SEGS = 1024 / (NSP * 32);   // segs per K-half: NSP=4 -> 8
    __shared__ __align__(16) char smem[49152];
    const int tid = threadIdx.x;
    const int l   = tid & 63;
    const int w   = tid >> 6;      // 0..7
    const int h   = w >> 2;        // k-half within slice
    const int f   = w & 3;         // col quad
    const int sp  = blockIdx.y;    // split index
    const int row0 = blockIdx.x * BM;
    const int k0 = sp * (DDIM / NSP);

    f32x16 acc1, acc2;
    #pragma unroll
    for (int r = 0; r < 16; ++r) { acc1[r] = 0.0f; acc2[r] = 0.0f; }

    const int h_s = w >> 2, s_s = (w >> 1) & 1, j4 = w & 1;
    const float* aSrc = x + (size_t)(row0 + (l & 31)) * DDIM + k0
                          + h_s * (SEGS * 32) + s_s * 16 + (l >> 5) * 8 + j4 * 4;
    auto loadA = [&](int t) -> float4 {
        return *(const float4*)(aSrc + (size_t)t * 32);
    };
    auto cvtWrite = [&](float4 xv, int buf) {
        float xs[4] = {xv.x, xv.y, xv.z, xv.w};
        f16x4 hi, lo;
        #pragma unroll
        for (int j = 0; j < 4; ++j) {
            f16 hh   = (f16)xs[j];
            float hf = (float)hh;
            hi[j] = hh;
            lo[j] = (f16)((xs[j] - hf) * 64.0f);
        }
        *(f16x4*)(smem + a_off(buf, h_s, s_s, 0) + l * 16 + j4 * 8) = hi;
        *(f16x4*)(smem + a_off(buf, h_s, s_s, 1) + l * 16 + j4 * 8) = lo;
    };

    const f16* bBase = wfrag + (size_t)f * 1024 + l * 8;
#define LOADB(t, H0, L0, H1, L1) do {                                       \
        const f16* _p = bBase + (size_t)(sp * (128 / NSP)                   \
                                         + h * (SEGS * 2) + (t) * 2) * 4096;\
        H0 = *(const f16x8*)_p;          L0 = *(const f16x8*)(_p + 512);    \
        H1 = *(const f16x8*)(_p + 4096); L1 = *(const f16x8*)(_p + 4608);   \
    } while (0)

    auto compute = [&](int buf, f16x8 Bh0, f16x8 Bl0, f16x8 Bh1, f16x8 Bl1) {
        #pragma unroll
        for (int s = 0; s < 2; ++s) {
            f16x8 Ah = *(const f16x8*)(smem + a_off(buf, h, s, 0) + l * 16);
            f16x8 Al = *(const f16x8*)(smem + a_off(buf, h, s, 1) + l * 16);
            f16x8 Bh = s ? Bh1 : Bh0;
            f16x8 Bl = s ? Bl1 : Bl0;
            acc1 = __builtin_amdgcn_mfma_f32_32x32x16_f16(Ah, Bh, acc1, 0, 0, 0);
            acc2 = __builtin_amdgcn_mfma_f32_32x32x16_f16(Ah, Bl, acc2, 0, 0, 0);
            acc2 = __builtin_amdgcn_mfma_f32_32x32x16_f16(Al, Bh, acc2, 0, 0, 0);
        }
    };

    float4 a0, a1, a2, a3;
    f16x8 b0h0, b0l0, b0h1, b0l1;
    f16x8 b1h0, b1l0, b1h1, b1l1;

    a0 = loadA(0); a1 = loadA(1); a2 = loadA(2); a3 = loadA(3);
    LOADB(0, b0h0, b0l0, b0h1, b0l1);
    LOADB(1, b1h0, b1l0, b1h1, b1l1);
    cvtWrite(a0, 0);
    cvtWrite(a1, 1);
    __syncthreads();

    for (int tb = 0; tb < SEGS; tb += 4) {
        compute(0, b0h0, b0l0, b0h1, b0l1);
        if (tb + 4 < SEGS) a0 = loadA(tb + 4);
        if (tb + 2 < SEGS) LOADB(tb + 2, b0h0, b0l0, b0h1, b0l1);
        cvtWrite(a2, 2);
        __syncthreads();

        compute(1, b1h0, b1l0, b1h1, b1l1);
        if (tb + 5 < SEGS) a1 = loadA(tb + 5);
        if (tb + 3 < SEGS) LOADB(tb + 3, b1h0, b1l0, b1h1, b1l1);
        cvtWrite(a3, 3);
        __syncthreads();

        compute(2, b0h0, b0l0, b0h1, b0l1);
        if (tb + 6 < SEGS) a2 = loadA(tb + 6);
        if (tb + 4 < SEGS) {
            LOADB(tb + 4, b0h0, b0l0, b0h1, b0l1);
            cvtWrite(a0, 0);
        }
        __syncthreads();

        compute(3, b1h0, b1l0, b1h1, b1l1);
        if (tb + 7 < SEGS) a3 = loadA(tb + 7);
        if (tb + 5 < SEGS) {
            LOADB(tb + 5, b1h0, b1l0, b1h1, b1l1);
            cvtWrite(a1, 1);
        }
        __syncthreads();
    }
#undef LOADB

    // ---- merge k-halves, write fp32 partial ----
    float* mg = (float*)(smem + 32768);    // [32][128]
    if (h == 1) {
        #pragma unroll
        for (int r = 0; r < 16; ++r) {
            float cv = fmaf(acc2[r], 0.015625f, acc1[r]);
            int row = (r & 3) + 8 * (r >> 2) + 4 * (l >> 5);
            int col = f * 32 + (l & 31);
            mg[row * 128 + col] = cv;
        }
    }
    __syncthreads();
    if (h == 0) {
        #pragma unroll
        for (int r = 0; r < 16; ++r) {
            float cv = fmaf(acc2[r], 0.015625f, acc1[r]);
            int row = (r & 3) + 8 * (r >> 2) + 4 * (l >> 5);
            int col = f * 32 + (l & 31);
            part[((size_t)sp * NROWS + row0 + row) * 128 + col] = cv + mg[row * 128 + col];
        }
    }
}

// ---------------- phase 2: reduce partials + noise + top-2 + softmax ----------------
template<int NSP>
__global__ __launch_bounds__(256) void reduce_gating(
    const float* __restrict__ part, const float* __restrict__ noise,
    float* __restrict__ out_w, float* __restrict__ out_idx,
    float* __restrict__ out_logits, float* __restrict__ out_probs)
{
    __shared__ float lgf[64 * 132];        // 33.8 KB
    const int tid = threadIdx.x;
    const int l   = tid & 63;
    const int w   = tid >> 6;              // 0..3
    const int row0 = blockIdx.x * 64;

    // ---- sum partials into lgf[64][132] ----
    #pragma unroll
    for (int q = 0; q < 8; ++q) {
        int idx = q * 256 + tid;           // 0..2047
        int r   = idx >> 5;                // row 0..63
        int c4  = idx & 31;                // float4 chunk 0..31
        float4 s = make_float4(0.f, 0.f, 0.f, 0.f);
        #pragma unroll
        for (int sp = 0; sp < NSP; ++sp) {
            float4 v = *(const float4*)(part + ((size_t)sp * NROWS + row0 + r) * 128 + c4 * 4);
            s.x += v.x; s.y += v.y; s.z += v.z; s.w += v.w;
        }
        *(float4*)(lgf + r * 132 + c4 * 4) = s;
    }
    __syncthreads();

    // ---- noise injection: 64 rows x 4 chunks of 16 ----
    {
        const int pr = tid & 63;
        const int pc = tid >> 6;           // 0..3
        const int n1 = row0 + pr;
        const float4* gl4 = (const float4*)(lgf + pr * 132 + pc * 16);
        const float4* nl4 = (const float4*)(lgf + pr * 132 + 64 + pc * 16);
        const float4* nz4 = (const float4*)(noise + (size_t)n1 * NE + pc * 16);
        float4* gw4 = (float4*)(lgf + pr * 132 + pc * 16);
        float4* ol4 = (float4*)(out_logits + (size_t)n1 * NE + pc * 16);
        #pragma unroll
        for (int q = 0; q < 4; ++q) {
            float4 G = gl4[q], NL = nl4[q], NZ = nz4[q];
            G.x += NZ.x * softplus_f(NL.x) * NSCALE;
            G.y += NZ.y * softplus_f(NL.y) * NSCALE;
            G.z += NZ.z * softplus_f(NL.z) * NSCALE;
            G.w += NZ.w * softplus_f(NL.w) * NSCALE;
            gw4[q] = G;
            ol4[q] = G;
        }
    }
    __syncthreads();

    // ---- per-row top-2 + softmax; 4 lanes/row x 64 rows (R4-verified) ----
    {
        const int g2   = l >> 2;           // row within wave's 16-row group
        const int c    = l & 3;            // expert chunk of 16
        const int row2 = w * 16 + g2;
        const int n2   = row0 + row2;

        float mv[16];
        {
            const float4* mr = (const float4*)(lgf + row2 * 132 + c * 16);
            #pragma unroll
            for (int q = 0; q < 4; ++q) {
                float4 v = mr[q];
                mv[q*4+0] = v.x; mv[q*4+1] = v.y; mv[q*4+2] = v.z; mv[q*4+3] = v.w;
            }
        }
        float v0 = -INFINITY, v1 = -INFINITY;
        int i0 = 0, i1 = 0;
        #pragma unroll
        for (int j = 0; j < 16; ++j) {
            float v = mv[j]; int e = c * 16 + j;
            if (v > v0) { v1 = v0; i1 = i0; v0 = v; i0 = e; }
            else if (v > v1) { v1 = v; i1 = e; }
        }
        #pragma unroll
        for (int m = 1; m <= 2; m <<= 1) {
            float ov0 = __shfl_xor(v0, m), ov1 = __shfl_xor(v1, m);
            int   oi0 = __shfl_xor(i0, m), oi1 = __shfl_xor(i1, m);
            if (ov0 > v0) {
                bool keep = (v0 > ov1);
                v1 = keep ? v0 : ov1; i1 = keep ? i0 : oi1;
                v0 = ov0; i0 = oi0;
            } else if (ov0 > v1) {
                v1 = ov0; i1 = oi0;
            }
        }
        const int srcl = l & 60;
        v0 = __shfl(v0, srcl); i0 = __shfl(i0, srcl);
        v1 = __shfl(v1, srcl); i1 = __shfl(i1, srcl);

        float se = 0.0f;
        #pragma unroll
        for (int j = 0; j < 16; ++j) se += expf(mv[j] - v0);
        se += __shfl_xor(se, 1); se += __shfl_xor(se, 2);
        float inv_se = 1.0f / se;

        float t  = expf(v1 - v0);
        float w0 = 1.0f / (1.0f + t);
        float w1 = t * w0;

        float pr[16], wt[16];
        #pragma unroll
        for (int j = 0; j < 16; ++j) {
            int e = c * 16 + j;
            pr[j] = expf(mv[j] - v0) * inv_se;
            wt[j] = (e == i0) ? w0 : ((e == i1) ? w1 : 0.0f);
        }
        #pragma unroll
        for (int q = 0; q < 4; ++q) {
            *(float4*)(out_probs + (size_t)n2 * NE + c * 16 + q * 4) =
                make_float4(pr[q*4+0], pr[q*4+1], pr[q*4+2], pr[q*4+3]);
            *(float4*)(out_w + (size_t)n2 * NE + c * 16 + q * 4) =
                make_float4(wt[q*4+0], wt[q*4+1], wt[q*4+2], wt[q*4+3]);
        }
        if (c == 0) {
            *(float2*)(out_idx + (size_t)n2 * 2) = make_float2((float)i0, (float)i1);
        }
    }
}

extern "C" void kernel_launch(void* const* d_in, const int* in_sizes, int n_in,
                              void* d_out, int out_size, void* d_ws, size_t ws_size,
                              hipStream_t stream) {
    (void)in_sizes; (void)n_in; (void)out_size;
    const float* x     = (const float*)d_in[0];
    const float* Wg    = (const float*)d_in[1];
    const float* Wn    = (const float*)d_in[2];
    const float* noise = (const float*)d_in[3];
    float* out        = (float*)d_out;
    float* out_w      = out;
    float* out_idx    = out + (size_t)NROWS * NE;
    float* out_logits = out_idx + (size_t)NROWS * 2;
    float* out_probs  = out_logits + (size_t)NROWS * NE;

    f16*   wfrag = (f16*)d_ws;                           // 1 MB
    float* part  = (float*)((char*)d_ws + (1 << 20));    // fp32 partials
    const size_t partBytes = (size_t)NROWS * 128 * 4;    // 8.39 MB per split

    wprep_kernel<<<128, 256, 0, stream>>>(Wg, Wn, wfrag);

    if (ws_size >= (1u << 20) + 4 * partBytes) {
        gemm_phase1<4><<<dim3(NROWS / BM, 4), 512, 0, stream>>>(x, wfrag, part);
        reduce_gating<4><<<NROWS / 64, 256, 0, stream>>>(
            part, noise, out_w, out_idx, out_logits, out_probs);
    } else {
        gemm_phase1<2><<<dim3(NROWS / BM, 2), 512, 0, stream>>>(x, wfrag, part);
        reduce_gating<2><<<NROWS / 64, 256, 0, stream>>>(
            part, noise, out_w, out_idx, out_logits, out_probs);
    }
}

// Round 18
// 58.188 us; speedup vs baseline: 1.2163x; 1.2163x over previous
//
#include <hip/hip_runtime.h>
#include <math.h>

// LinearGating: B=4,S=4096,D=2048,E=64,K=2 -> N=16384 rows
// out (flat f32): [weights N*64][indices N*2 (as float)][logits N*64][probs N*64]
//
// fp16 split-3 MFMA GEMM: C[N x 128] = X[N x 2048] @ [Wg|Wn]
//   x = h + d, w = H + D;  acc1 += h*H ; acc2 += h*(D*2^6) + (d*2^6)*H
//   C = acc1 + acc2 * 2^-6
// R18: CONTIGUOUS HBM STREAMING of x. Super-segments of k=256: each wave
// loads 4 whole row-chunks as 1KB-contiguous instructions (vs 32B scatter in
// R4-R17 -- the invariant ~1.3 TB/s fetch ceiling), converts once to f16
// hi/lo, writes rotation-swizzled LDS tile (slot=(chunk+2r)&63: b128-aligned
// fragment reads, ~4-way conflicts). ONE barrier per super-seg (8 total).
// B: R15's wave-private global->reg. Unpinned; all indices static.

typedef _Float16 f16;
typedef f16  f16x4  __attribute__((ext_vector_type(4)));
typedef f16  f16x8  __attribute__((ext_vector_type(8)));
typedef float f32x16 __attribute__((ext_vector_type(16)));

constexpr int NROWS = 16384;
constexpr int DDIM  = 2048;
constexpr int NE    = 64;
constexpr int BM    = 32;
constexpr int SS    = 256;            // k per super-segment
constexpr int NSS   = DDIM / SS;      // 8
constexpr float NSCALE = 1.0f / 4096.0f;

__device__ __forceinline__ float softplus_f(float x) {
    return fmaxf(x, 0.0f) + log1pf(expf(-fabsf(x)));
}

// ---------------- W prep: fragment-ordered fp16 {H, D*2^6} ----------------
// blob(S 0..127, f 0..3, v 0..1): lane l, elem j = Wcat[S*16+(l>>5)*8+j][f*32+(l&31)]
__global__ __launch_bounds__(256) void wprep_kernel(
    const float* __restrict__ Wg, const float* __restrict__ Wn,
    f16* __restrict__ ws)
{
    int t = blockIdx.x * 256 + threadIdx.x;    // 0..32767
    int S = t >> 8;
    int f = (t >> 6) & 3;
    int l = t & 63;
    int k0  = S * 16 + (l >> 5) * 8;
    int col = f * 32 + (l & 31);
    const float* src = (col < NE) ? (Wg + col) : (Wn + col - NE);
    f16x8 hp, lp;
    #pragma unroll
    for (int j = 0; j < 8; ++j) {
        float w  = src[(size_t)(k0 + j) * NE];
        f16 h    = (f16)w;
        float hf = (float)h;
        hp[j] = h;
        lp[j] = (f16)((w - hf) * 64.0f);
    }
    size_t base = (size_t)(S * 4 + f) * 1024;   // f16 units
    *(f16x8*)(ws + base + l * 8)       = hp;
    *(f16x8*)(ws + base + 512 + l * 8) = lp;
}

// ---------------- main fused kernel ----------------
// LDS: 2 bufs x 32KB. buf tile: [32 rows][1KB]: hi slots 0..63 (8B each,
// bytes 0..511), lo slots at +512. slot = (chunk + 2*row) & 63, chunk=k/4.
__global__ __launch_bounds__(512, 4) void gemm_gating(
    const float* __restrict__ x, const f16* __restrict__ wfrag,
    const float* __restrict__ noise,
    float* __restrict__ out_w, float* __restrict__ out_idx,
    float* __restrict__ out_logits, float* __restrict__ out_probs)
{
    __shared__ __align__(16) char smem[65536];
    const int tid = threadIdx.x;
    const int l   = tid & 63;
    const int w   = tid >> 6;      // 0..7
    const int h   = w >> 2;        // compute: k-half of each super-seg
    const int f   = w & 3;         // compute: col quad (cols f*32..+31)
    const int row0 = blockIdx.x * BM;

    f32x16 acc1, acc2;
    #pragma unroll
    for (int r = 0; r < 16; ++r) { acc1[r] = 0.0f; acc2[r] = 0.0f; }

    // --- A staging: wave w owns rows w*4..w*4+3; 1KB contiguous per row ---
    const int srow = w * 4;
    const float* aSrc = x + (size_t)(row0 + srow) * DDIM + l * 4;
    float4 av0, av1, av2, av3;
    auto loadA = [&](int ss) {
        const float* p = aSrc + ss * SS;
        av0 = *(const float4*)(p);
        av1 = *(const float4*)(p + DDIM);
        av2 = *(const float4*)(p + 2 * DDIM);
        av3 = *(const float4*)(p + 3 * DDIM);
    };
    auto cvtWrite = [&](int buf) {
        float4 vv[4] = {av0, av1, av2, av3};
        #pragma unroll
        for (int i = 0; i < 4; ++i) {
            int r = srow + i;
            float xs[4] = {vv[i].x, vv[i].y, vv[i].z, vv[i].w};
            f16x4 hi, lo;
            #pragma unroll
            for (int j = 0; j < 4; ++j) {
                f16 hh   = (f16)xs[j];
                float hf = (float)hh;
                hi[j] = hh;
                lo[j] = (f16)((xs[j] - hf) * 64.0f);
            }
            int slot = (l + 2 * r) & 63;
            char* base = smem + buf * 32768 + r * 1024;
            *(f16x4*)(base + slot * 8)       = hi;
            *(f16x4*)(base + 512 + slot * 8) = lo;
        }
    };

    // --- A fragment reads (compute): row R=l&31, k-group kg=l>>5 ---
    const int R  = l & 31;
    const int kg = l >> 5;
    auto readA = [&](int buf, int T_loc, int s, f16x8& Ah, f16x8& Al) {
        int ch   = T_loc * 8 + s * 4 + kg * 2;        // even
        int slot = (ch + 2 * R) & 63;                 // even, no wrap mid-frag
        const char* base = smem + buf * 32768 + R * 1024;
        Ah = *(const f16x8*)(base + slot * 8);
        Al = *(const f16x8*)(base + 512 + slot * 8);
    };

    // --- B: wave-private, global->reg. k32-slice T: blobs S=2T,2T+1 ---
    const f16* bBase = wfrag + (size_t)f * 1024 + l * 8;
#define LOADB(T, H0, L0, H1, L1) do {                                       \
        const f16* _p = bBase + (size_t)(T) * 2 * 4096;                     \
        H0 = *(const f16x8*)_p;          L0 = *(const f16x8*)(_p + 512);    \
        H1 = *(const f16x8*)(_p + 4096); L1 = *(const f16x8*)(_p + 4608);   \
    } while (0)

    auto computeSub = [&](int buf, int T_loc,
                          f16x8 Bh0, f16x8 Bl0, f16x8 Bh1, f16x8 Bl1) {
        f16x8 Ah, Al;
        readA(buf, T_loc, 0, Ah, Al);
        acc1 = __builtin_amdgcn_mfma_f32_32x32x16_f16(Ah, Bh0, acc1, 0, 0, 0);
        acc2 = __builtin_amdgcn_mfma_f32_32x32x16_f16(Ah, Bl0, acc2, 0, 0, 0);
        acc2 = __builtin_amdgcn_mfma_f32_32x32x16_f16(Al, Bh0, acc2, 0, 0, 0);
        readA(buf, T_loc, 1, Ah, Al);
        acc1 = __builtin_amdgcn_mfma_f32_32x32x16_f16(Ah, Bh1, acc1, 0, 0, 0);
        acc2 = __builtin_amdgcn_mfma_f32_32x32x16_f16(Ah, Bl1, acc2, 0, 0, 0);
        acc2 = __builtin_amdgcn_mfma_f32_32x32x16_f16(Al, Bh1, acc2, 0, 0, 0);
    };

    f16x8 b0h0, b0l0, b0h1, b0l1;   // B set 0 (even sub-segs)
    f16x8 b1h0, b1l0, b1h1, b1l1;   // B set 1 (odd sub-segs)

    // -------- prologue --------
    loadA(0);
    LOADB(h * 4 + 0, b0h0, b0l0, b0h1, b0l1);
    LOADB(h * 4 + 1, b1h0, b1l0, b1h1, b1l1);
    cvtWrite(0);

    // -------- main loop: 8 super-segs, ONE barrier each --------
    for (int ss = 0; ss < NSS; ++ss) {
        __syncthreads();                       // buf (ss&1) ready
        const int buf = ss & 1;
        const int T0  = ss * 8 + h * 4;
        if (ss + 1 < NSS) loadA(ss + 1);

        computeSub(buf, h * 4 + 0, b0h0, b0l0, b0h1, b0l1);
        LOADB(T0 + 2, b0h0, b0l0, b0h1, b0l1);
        computeSub(buf, h * 4 + 1, b1h0, b1l0, b1h1, b1l1);
        LOADB(T0 + 3, b1h0, b1l0, b1h1, b1l1);
        computeSub(buf, h * 4 + 2, b0h0, b0l0, b0h1, b0l1);
        if (ss + 1 < NSS) LOADB(T0 + 8, b0h0, b0l0, b0h1, b0l1);
        computeSub(buf, h * 4 + 3, b1h0, b1l0, b1h1, b1l1);
        if (ss + 1 < NSS) {
            LOADB(T0 + 9, b1h0, b1l0, b1h1, b1l1);
            cvtWrite(buf ^ 1);                 // super-seg ss+1 -> other buf
        }
    }
    __syncthreads();
#undef LOADB

    // ---- merge K-halves: h=1 waves write partial, h=0 adds ----
    float* mg = (float*)(smem + 32768);    // [32][128] (buf1 region)
    if (h == 1) {
        #pragma unroll
        for (int r = 0; r < 16; ++r) {
            float cv = fmaf(acc2[r], 0.015625f, acc1[r]);
            int row = (r & 3) + 8 * (r >> 2) + 4 * (l >> 5);
            int col = f * 32 + (l & 31);
            mg[row * 128 + col] = cv;
        }
    }
    __syncthreads();

    float* lgf = (float*)smem;             // [32][132] (buf0 region)
    if (h == 0) {
        #pragma unroll
        for (int r = 0; r < 16; ++r) {
            float cv = fmaf(acc2[r], 0.015625f, acc1[r]);
            int row = (r & 3) + 8 * (r >> 2) + 4 * (l >> 5);
            int col = f * 32 + (l & 31);
            lgf[row * 132 + col] = cv + mg[row * 128 + col];
        }
    }
    __syncthreads();

    // ---- phase1: noise injection; 512 thr = 32 rows x 16 float4-chunks ----
    {
        const int pr = tid & 31;           // row
        const int c4 = tid >> 5;           // float4 chunk 0..15
        const int n1 = row0 + pr;
        float4 G  = *(const float4*)(lgf + pr * 132 + c4 * 4);
        float4 NL = *(const float4*)(lgf + pr * 132 + 64 + c4 * 4);
        float4 NZ = *(const float4*)(noise + (size_t)n1 * NE + c4 * 4);
        G.x += NZ.x * softplus_f(NL.x) * NSCALE;
        G.y += NZ.y * softplus_f(NL.y) * NSCALE;
        G.z += NZ.z * softplus_f(NL.z) * NSCALE;
        G.w += NZ.w * softplus_f(NL.w) * NSCALE;
        *(float4*)(lgf + pr * 132 + c4 * 4) = G;
        *(float4*)(out_logits + (size_t)n1 * NE + c4 * 4) = G;
    }
    __syncthreads();

    // ---- phase2: per-row top-2 + softmax; waves 0..3, 8 lanes/row ----
    if (w < 4) {
        const int g2   = l >> 3;           // row within wave's 8-row group
        const int c    = l & 7;            // expert chunk of 8
        const int row2 = w * 8 + g2;
        const int n2   = row0 + row2;

        float mv[8];
        {
            const float4* mr = (const float4*)(lgf + row2 * 132 + c * 8);
            float4 m0 = mr[0], m1 = mr[1];
            mv[0]=m0.x; mv[1]=m0.y; mv[2]=m0.z; mv[3]=m0.w;
            mv[4]=m1.x; mv[5]=m1.y; mv[6]=m1.z; mv[7]=m1.w;
        }
        float v0 = -INFINITY, v1 = -INFINITY;
        int i0 = 0, i1 = 0;
        #pragma unroll
        for (int j = 0; j < 8; ++j) {
            float v = mv[j]; int e = c * 8 + j;
            if (v > v0) { v1 = v0; i1 = i0; v0 = v; i0 = e; }
            else if (v > v1) { v1 = v; i1 = e; }
        }
        #pragma unroll
        for (int m = 1; m <= 4; m <<= 1) {
            float ov0 = __shfl_xor(v0, m), ov1 = __shfl_xor(v1, m);
            int   oi0 = __shfl_xor(i0, m), oi1 = __shfl_xor(i1, m);
            if (ov0 > v0) {
                bool keep = (v0 > ov1);
                v1 = keep ? v0 : ov1; i1 = keep ? i0 : oi1;
                v0 = ov0; i0 = oi0;
            } else if (ov0 > v1) {
                v1 = ov0; i1 = oi0;
            }
        }
        const int srcl = l & 56;
        v0 = __shfl(v0, srcl); i0 = __shfl(i0, srcl);
        v1 = __shfl(v1, srcl); i1 = __shfl(i1, srcl);

        float se = 0.0f;
        #pragma unroll
        for (int j = 0; j < 8; ++j) se += expf(mv[j] - v0);
        se += __shfl_xor(se, 1); se += __shfl_xor(se, 2); se += __shfl_xor(se, 4);
        float inv_se = 1.0f / se;

        float t  = expf(v1 - v0);
        float w0 = 1.0f / (1.0f + t);
        float w1 = t * w0;

        float pr[8], wt[8];
        #pragma unroll
        for (int j = 0; j < 8; ++j) {
            int e = c * 8 + j;
            pr[j] = expf(mv[j] - v0) * inv_se;
            wt[j] = (e == i0) ? w0 : ((e == i1) ? w1 : 0.0f);
        }
        *(float4*)(out_probs + (size_t)n2 * NE + c * 8)     = make_float4(pr[0], pr[1], pr[2], pr[3]);
        *(float4*)(out_probs + (size_t)n2 * NE + c * 8 + 4) = make_float4(pr[4], pr[5], pr[6], pr[7]);
        *(float4*)(out_w + (size_t)n2 * NE + c * 8)         = make_float4(wt[0], wt[1], wt[2], wt[3]);
        *(float4*)(out_w + (size_t)n2 * NE + c * 8 + 4)     = make_float4(wt[4], wt[5], wt[6], wt[7]);
        if (c == 0) {
            *(float2*)(out_idx + (size_t)n2 * 2) = make_float2((float)i0, (float)i1);
        }
    }
}

extern "C" void kernel_launch(void* const* d_in, const int* in_sizes, int n_in,
                              void* d_out, int out_size, void* d_ws, size_t ws_size,
                              hipStream_t stream) {
    (void)in_sizes; (void)n_in; (void)ws_size; (void)out_size;
    const float* x     = (const float*)d_in[0];
    const float* Wg    = (const float*)d_in[1];
    const float* Wn    = (const float*)d_in[2];
    const float* noise = (const float*)d_in[3];
    float* out        = (float*)d_out;
    float* out_w      = out;
    float* out_idx    = out + (size_t)NROWS * NE;
    float* out_logits = out_idx + (size_t)NROWS * 2;
    float* out_probs  = out_logits + (size_t)NROWS * NE;
    f16* wfrag = (f16*)d_ws;   // 1 MB

    wprep_kernel<<<128, 256, 0, stream>>>(Wg, Wn, wfrag);
    gemm_gating<<<NROWS / BM, 512, 0, stream>>>(
        x, wfrag, noise, out_w, out_idx, out_logits, out_probs);
}

// Round 20
// 54.845 us; speedup vs baseline: 1.2905x; 1.0609x over previous
//
#include <hip/hip_runtime.h>
#include <math.h>

// LinearGating: B=4,S=4096,D=2048,E=64,K=2 -> N=16384 rows
// out (flat f32): [weights N*64][indices N*2 (as float)][logits N*64][probs N*64]
//
// fp16 split-3 MFMA GEMM: C[N x 128] = X[N x 2048] @ [Wg|Wn]
//   x = h + d, w = H + D;  acc1 += h*H ; acc2 += h*(D*2^6) + (d*2^6)*H
//   C = acc1 + acc2 * 2^-6
// R19b = R15 + REGISTER KEEP-ALIVE (compile-fixed: per-32-bit-component
// "v" inputs; 128-bit aggregates are not valid asm operands). R15's VGPR=48
// proves the compiler rematerialized the B/A pipeline loads at use
// (depth-0 -> L2 latency exposed per segment). KEEP pins each loaded value
// live BEFORE the barrier preceding its consuming segment.

typedef _Float16 f16;
typedef f16  f16x4  __attribute__((ext_vector_type(4)));
typedef f16  f16x8  __attribute__((ext_vector_type(8)));
typedef float f32x4v __attribute__((ext_vector_type(4)));
typedef float f32x16 __attribute__((ext_vector_type(16)));

constexpr int NROWS = 16384;
constexpr int DDIM  = 2048;
constexpr int NE    = 64;
constexpr int BM    = 32;
constexpr int KI    = 32;                 // k per segment per half
constexpr float NSCALE = 1.0f / 4096.0f;

__device__ __forceinline__ int a_off(int buf, int h, int s, int v) {
    return (((buf * 2 + h) * 2 + s) * 2 + v) * 1024;
}

__device__ __forceinline__ float softplus_f(float x) {
    return fmaxf(x, 0.0f) + log1pf(expf(-fabsf(x)));
}

__device__ __forceinline__ void keep_f4(const float4& v) {
    asm volatile("" :: "v"(v.x), "v"(v.y), "v"(v.z), "v"(v.w));
}
__device__ __forceinline__ void keep_h8(const f16x8& v) {
    f32x4v t = __builtin_bit_cast(f32x4v, v);
    asm volatile("" :: "v"(t[0]), "v"(t[1]), "v"(t[2]), "v"(t[3]));
}
#define KEEPB(H0, L0, H1, L1) do { keep_h8(H0); keep_h8(L0); keep_h8(H1); keep_h8(L1); } while (0)

// ---------------- W prep: fragment-ordered fp16 {H, D*2^6} ----------------
// blob(S 0..127, f 0..3, v 0..1): lane l, elem j = Wcat[S*16+(l>>5)*8+j][f*32+(l&31)]
__global__ __launch_bounds__(256) void wprep_kernel(
    const float* __restrict__ Wg, const float* __restrict__ Wn,
    f16* __restrict__ ws)
{
    int t = blockIdx.x * 256 + threadIdx.x;    // 0..32767
    int S = t >> 8;
    int f = (t >> 6) & 3;
    int l = t & 63;
    int k0  = S * 16 + (l >> 5) * 8;
    int col = f * 32 + (l & 31);
    const float* src = (col < NE) ? (Wg + col) : (Wn + col - NE);
    f16x8 hp, lp;
    #pragma unroll
    for (int j = 0; j < 8; ++j) {
        float w  = src[(size_t)(k0 + j) * NE];
        f16 h    = (f16)w;
        float hf = (float)h;
        hp[j] = h;
        lp[j] = (f16)((w - hf) * 64.0f);
    }
    size_t base = (size_t)(S * 4 + f) * 1024;   // f16 units
    *(f16x8*)(ws + base + l * 8)       = hp;
    *(f16x8*)(ws + base + 512 + l * 8) = lp;
}

// ---------------- main fused kernel ----------------
__global__ __launch_bounds__(512, 4) void gemm_gating(
    const float* __restrict__ x, const f16* __restrict__ wfrag,
    const float* __restrict__ noise,
    float* __restrict__ out_w, float* __restrict__ out_idx,
    float* __restrict__ out_logits, float* __restrict__ out_probs)
{
    __shared__ __align__(16) char smem[49152];
    const int tid = threadIdx.x;
    const int l   = tid & 63;
    const int w   = tid >> 6;      // 0..7
    const int h   = w >> 2;        // compute: k-half
    const int f   = w & 3;         // compute: col quad (cols f*32..+31)
    const int row0 = blockIdx.x * BM;

    f32x16 acc1, acc2;
    #pragma unroll
    for (int r = 0; r < 16; ++r) { acc1[r] = 0.0f; acc2[r] = 0.0f; }

    // --- A staging role: wave w owns (h_s = w>>2, s_s = (w>>1)&1, j4 = w&1) ---
    const int h_s = w >> 2, s_s = (w >> 1) & 1, j4 = w & 1;
    const float* aSrc = x + (size_t)(row0 + (l & 31)) * DDIM
                          + h_s * 1024 + s_s * 16 + (l >> 5) * 8 + j4 * 4;
    auto loadA = [&](int t) -> float4 {
        return *(const float4*)(aSrc + (size_t)t * KI);
    };
    auto cvtWrite = [&](float4 xv, int buf) {   // buf is compile-time static
        float xs[4] = {xv.x, xv.y, xv.z, xv.w};
        f16x4 hi, lo;
        #pragma unroll
        for (int j = 0; j < 4; ++j) {
            f16 hh   = (f16)xs[j];
            float hf = (float)hh;
            hi[j] = hh;
            lo[j] = (f16)((xs[j] - hf) * 64.0f);
        }
        *(f16x4*)(smem + a_off(buf, h_s, s_s, 0) + l * 16 + j4 * 8) = hi;
        *(f16x4*)(smem + a_off(buf, h_s, s_s, 1) + l * 16 + j4 * 8) = lo;
    };

    // --- B: wave-private, global->reg. Slice S = h*64 + t*2 + s ---
    const f16* bBase = wfrag + (size_t)f * 1024 + l * 8;
#define LOADB(t, H0, L0, H1, L1) do {                                       \
        const f16* _p = bBase + (size_t)(h * 64 + (t) * 2) * 4096;          \
        H0 = *(const f16x8*)_p;          L0 = *(const f16x8*)(_p + 512);    \
        H1 = *(const f16x8*)(_p + 4096); L1 = *(const f16x8*)(_p + 4608);   \
    } while (0)

    auto compute = [&](int buf, f16x8 Bh0, f16x8 Bl0, f16x8 Bh1, f16x8 Bl1) {
        #pragma unroll
        for (int s = 0; s < 2; ++s) {
            f16x8 Ah = *(const f16x8*)(smem + a_off(buf, h, s, 0) + l * 16);
            f16x8 Al = *(const f16x8*)(smem + a_off(buf, h, s, 1) + l * 16);
            f16x8 Bh = s ? Bh1 : Bh0;
            f16x8 Bl = s ? Bl1 : Bl0;
            acc1 = __builtin_amdgcn_mfma_f32_32x32x16_f16(Ah, Bh, acc1, 0, 0, 0);
            acc2 = __builtin_amdgcn_mfma_f32_32x32x16_f16(Ah, Bl, acc2, 0, 0, 0);
            acc2 = __builtin_amdgcn_mfma_f32_32x32x16_f16(Al, Bh, acc2, 0, 0, 0);
        }
    };

    float4 a0, a1, a2, a3;
    f16x8 b0h0, b0l0, b0h1, b0l1;   // B set 0 (even segs)
    f16x8 b1h0, b1l0, b1h1, b1l1;   // B set 1 (odd segs)

    // -------- prologue: A(0..3) regs, B(0),B(1) regs, bufs 0,1 written --------
    a0 = loadA(0); a1 = loadA(1); a2 = loadA(2); a3 = loadA(3);
    LOADB(0, b0h0, b0l0, b0h1, b0l1);
    LOADB(1, b1h0, b1l0, b1h1, b1l1);
    cvtWrite(a0, 0);
    cvtWrite(a1, 1);
    KEEPB(b0h0, b0l0, b0h1, b0l1);
    KEEPB(b1h0, b1l0, b1h1, b1l1);
    keep_f4(a2); keep_f4(a3);
    __syncthreads();

    // -------- main loop: 8 trips x 4 segs, all indices static --------
    for (int tb = 0; tb < 32; tb += 4) {
        // seg tb+0: buf0, Bset0
        compute(0, b0h0, b0l0, b0h1, b0l1);
        if (tb + 4 < 32) a0 = loadA(tb + 4);
        if (tb + 2 < 32) LOADB(tb + 2, b0h0, b0l0, b0h1, b0l1);
        cvtWrite(a2, 2);                       // seg tb+2 -> buf2
        KEEPB(b1h0, b1l0, b1h1, b1l1);         // set1 live across barrier
        if (tb + 2 < 32) KEEPB(b0h0, b0l0, b0h1, b0l1);  // new set0 issued pre-barrier
        keep_f4(a3);
        __syncthreads();
        // seg tb+1: buf1, Bset1
        compute(1, b1h0, b1l0, b1h1, b1l1);
        if (tb + 5 < 32) a1 = loadA(tb + 5);
        if (tb + 3 < 32) LOADB(tb + 3, b1h0, b1l0, b1h1, b1l1);
        cvtWrite(a3, 3);                       // seg tb+3 -> buf3
        KEEPB(b0h0, b0l0, b0h1, b0l1);
        if (tb + 3 < 32) KEEPB(b1h0, b1l0, b1h1, b1l1);
        if (tb + 4 < 32) keep_f4(a0);
        __syncthreads();
        // seg tb+2: buf2, Bset0
        compute(2, b0h0, b0l0, b0h1, b0l1);
        if (tb + 6 < 32) a2 = loadA(tb + 6);
        if (tb + 4 < 32) {
            LOADB(tb + 4, b0h0, b0l0, b0h1, b0l1);
            cvtWrite(a0, 0);                   // seg tb+4 -> buf0
        }
        KEEPB(b1h0, b1l0, b1h1, b1l1);
        if (tb + 4 < 32) KEEPB(b0h0, b0l0, b0h1, b0l1);
        if (tb + 5 < 32) keep_f4(a1);
        __syncthreads();
        // seg tb+3: buf3, Bset1
        compute(3, b1h0, b1l0, b1h1, b1l1);
        if (tb + 7 < 32) a3 = loadA(tb + 7);
        if (tb + 5 < 32) {
            LOADB(tb + 5, b1h0, b1l0, b1h1, b1l1);
            cvtWrite(a1, 1);                   // seg tb+5 -> buf1
        }
        KEEPB(b0h0, b0l0, b0h1, b0l1);
        if (tb + 5 < 32) KEEPB(b1h0, b1l0, b1h1, b1l1);
        if (tb + 6 < 32) keep_f4(a2);
        __syncthreads();
    }
#undef LOADB

    // ---- merge K-halves: h=1 waves write partial, h=0 adds ----
    float* mg = (float*)(smem + 32768);    // [32][128]
    if (h == 1) {
        #pragma unroll
        for (int r = 0; r < 16; ++r) {
            float cv = fmaf(acc2[r], 0.015625f, acc1[r]);
            int row = (r & 3) + 8 * (r >> 2) + 4 * (l >> 5);
            int col = f * 32 + (l & 31);
            mg[row * 128 + col] = cv;
        }
    }
    __syncthreads();

    float* lgf = (float*)smem;             // [32][132]
    if (h == 0) {
        #pragma unroll
        for (int r = 0; r < 16; ++r) {
            float cv = fmaf(acc2[r], 0.015625f, acc1[r]);
            int row = (r & 3) + 8 * (r >> 2) + 4 * (l >> 5);
            int col = f * 32 + (l & 31);
            lgf[row * 132 + col] = cv + mg[row * 128 + col];
        }
    }
    __syncthreads();

    // ---- phase1: noise injection; 512 thr = 32 rows x 16 float4-chunks ----
    {
        const int pr = tid & 31;           // row
        const int c4 = tid >> 5;           // float4 chunk 0..15
        const int n1 = row0 + pr;
        float4 G  = *(const float4*)(lgf + pr * 132 + c4 * 4);
        float4 NL = *(const float4*)(lgf + pr * 132 + 64 + c4 * 4);
        float4 NZ = *(const float4*)(noise + (size_t)n1 * NE + c4 * 4);
        G.x += NZ.x * softplus_f(NL.x) * NSCALE;
        G.y += NZ.y * softplus_f(NL.y) * NSCALE;
        G.z += NZ.z * softplus_f(NL.z) * NSCALE;
        G.w += NZ.w * softplus_f(NL.w) * NSCALE;
        *(float4*)(lgf + pr * 132 + c4 * 4) = G;
        *(float4*)(out_logits + (size_t)n1 * NE + c4 * 4) = G;
    }
    __syncthreads();

    // ---- phase2: per-row top-2 + softmax; waves 0..3, 8 lanes/row ----
    if (w < 4) {
        const int g2   = l >> 3;           // row within wave's 8-row group
        const int c    = l & 7;            // expert chunk of 8
        const int row2 = w * 8 + g2;
        const int n2   = row0 + row2;

        float mv[8];
        {
            const float4* mr = (const float4*)(lgf + row2 * 132 + c * 8);
            float4 m0 = mr[0], m1 = mr[1];
            mv[0]=m0.x; mv[1]=m0.y; mv[2]=m0.z; mv[3]=m0.w;
            mv[4]=m1.x; mv[5]=m1.y; mv[6]=m1.z; mv[7]=m1.w;
        }
        float v0 = -INFINITY, v1 = -INFINITY;
        int i0 = 0, i1 = 0;
        #pragma unroll
        for (int j = 0; j < 8; ++j) {
            float v = mv[j]; int e = c * 8 + j;
            if (v > v0) { v1 = v0; i1 = i0; v0 = v; i0 = e; }
            else if (v > v1) { v1 = v; i1 = e; }
        }
        #pragma unroll
        for (int m = 1; m <= 4; m <<= 1) {
            float ov0 = __shfl_xor(v0, m), ov1 = __shfl_xor(v1, m);
            int   oi0 = __shfl_xor(i0, m), oi1 = __shfl_xor(i1, m);
            if (ov0 > v0) {
                bool keep = (v0 > ov1);
                v1 = keep ? v0 : ov1; i1 = keep ? i0 : oi1;
                v0 = ov0; i0 = oi0;
            } else if (ov0 > v1) {
                v1 = ov0; i1 = oi0;
            }
        }
        const int srcl = l & 56;
        v0 = __shfl(v0, srcl); i0 = __shfl(i0, srcl);
        v1 = __shfl(v1, srcl); i1 = __shfl(i1, srcl);

        float se = 0.0f;
        #pragma unroll
        for (int j = 0; j < 8; ++j) se += expf(mv[j] - v0);
        se += __shfl_xor(se, 1); se += __shfl_xor(se, 2); se += __shfl_xor(se, 4);
        float inv_se = 1.0f / se;

        float t  = expf(v1 - v0);
        float w0 = 1.0f / (1.0f + t);
        float w1 = t * w0;

        float pr[8], wt[8];
        #pragma unroll
        for (int j = 0; j < 8; ++j) {
            int e = c * 8 + j;
            pr[j] = expf(mv[j] - v0) * inv_se;
            wt[j] = (e == i0) ? w0 : ((e == i1) ? w1 : 0.0f);
        }
        *(float4*)(out_probs + (size_t)n2 * NE + c * 8)     = make_float4(pr[0], pr[1], pr[2], pr[3]);
        *(float4*)(out_probs + (size_t)n2 * NE + c * 8 + 4) = make_float4(pr[4], pr[5], pr[6], pr[7]);
        *(float4*)(out_w + (size_t)n2 * NE + c * 8)         = make_float4(wt[0], wt[1], wt[2], wt[3]);
        *(float4*)(out_w + (size_t)n2 * NE + c * 8 + 4)     = make_float4(wt[4], wt[5], wt[6], wt[7]);
        if (c == 0) {
            *(float2*)(out_idx + (size_t)n2 * 2) = make_float2((float)i0, (float)i1);
        }
    }
}

extern "C" void kernel_launch(void* const* d_in, const int* in_sizes, int n_in,
                              void* d_out, int out_size, void* d_ws, size_t ws_size,
                              hipStream_t stream) {
    (void)in_sizes; (void)n_in; (void)ws_size; (void)out_size;
    const float* x     = (const float*)d_in[0];
    const float* Wg    = (const float*)d_in[1];
    const float* Wn    = (const float*)d_in[2];
    const float* noise = (const float*)d_in[3];
    float* out        = (float*)d_out;
    float* out_w      = out;
    float* out_idx    = out + (size_t)NROWS * NE;
    float* out_logits = out_idx + (size_t)NROWS * 2;
    float* out_probs  = out_logits + (size_t)NROWS * NE;
    f16* wfrag = (f16*)d_ws;   // 1 MB

    wprep_kernel<<<128, 256, 0, stream>>>(Wg, Wn, wfrag);
    gemm_gating<<<NROWS / BM, 512, 0, stream>>>(
        x, wfrag, noise, out_w, out_idx, out_logits, out_probs);
}

// Round 21
// 52.638 us; speedup vs baseline: 1.3446x; 1.0419x over previous
//
#include <hip/hip_runtime.h>
#include <math.h>

// LinearGating: B=4,S=4096,D=2048,E=64,K=2 -> N=16384 rows
// out (flat f32): [weights N*64][indices N*2 (as float)][logits N*64][probs N*64]
//
// fp16 split-3 MFMA GEMM: C[N x 128] = X[N x 2048] @ [Wg|Wn]
//   x = h + d, w = H + D;  acc1 += h*H ; acc2 += h*(D*2^6) + (d*2^6)*H
//   C = acc1 + acc2 * 2^-6
// R21 = R15 (best, 52.5us) with the steady loop made BRANCH-FREE: trips
// tb=0..24 have unconditional load/stage bodies (indices provably <=31),
// tail trip tb=28 peeled with explicit epilogue. Loads under branches can't
// hoist across __syncthreads; unconditional ones can. No keeps, no pins.

typedef _Float16 f16;
typedef f16  f16x4  __attribute__((ext_vector_type(4)));
typedef f16  f16x8  __attribute__((ext_vector_type(8)));
typedef float f32x16 __attribute__((ext_vector_type(16)));

constexpr int NROWS = 16384;
constexpr int DDIM  = 2048;
constexpr int NE    = 64;
constexpr int BM    = 32;
constexpr int KI    = 32;                 // k per segment per half
constexpr float NSCALE = 1.0f / 4096.0f;

__device__ __forceinline__ int a_off(int buf, int h, int s, int v) {
    return (((buf * 2 + h) * 2 + s) * 2 + v) * 1024;
}

__device__ __forceinline__ float softplus_f(float x) {
    return fmaxf(x, 0.0f) + log1pf(expf(-fabsf(x)));
}

// ---------------- W prep: fragment-ordered fp16 {H, D*2^6} ----------------
// blob(S 0..127, f 0..3, v 0..1): lane l, elem j = Wcat[S*16+(l>>5)*8+j][f*32+(l&31)]
__global__ __launch_bounds__(256) void wprep_kernel(
    const float* __restrict__ Wg, const float* __restrict__ Wn,
    f16* __restrict__ ws)
{
    int t = blockIdx.x * 256 + threadIdx.x;    // 0..32767
    int S = t >> 8;
    int f = (t >> 6) & 3;
    int l = t & 63;
    int k0  = S * 16 + (l >> 5) * 8;
    int col = f * 32 + (l & 31);
    const float* src = (col < NE) ? (Wg + col) : (Wn + col - NE);
    f16x8 hp, lp;
    #pragma unroll
    for (int j = 0; j < 8; ++j) {
        float w  = src[(size_t)(k0 + j) * NE];
        f16 h    = (f16)w;
        float hf = (float)h;
        hp[j] = h;
        lp[j] = (f16)((w - hf) * 64.0f);
    }
    size_t base = (size_t)(S * 4 + f) * 1024;   // f16 units
    *(f16x8*)(ws + base + l * 8)       = hp;
    *(f16x8*)(ws + base + 512 + l * 8) = lp;
}

// ---------------- main fused kernel ----------------
__global__ __launch_bounds__(512, 4) void gemm_gating(
    const float* __restrict__ x, const f16* __restrict__ wfrag,
    const float* __restrict__ noise,
    float* __restrict__ out_w, float* __restrict__ out_idx,
    float* __restrict__ out_logits, float* __restrict__ out_probs)
{
    __shared__ __align__(16) char smem[49152];
    const int tid = threadIdx.x;
    const int l   = tid & 63;
    const int w   = tid >> 6;      // 0..7
    const int h   = w >> 2;        // compute: k-half
    const int f   = w & 3;         // compute: col quad (cols f*32..+31)
    const int row0 = blockIdx.x * BM;

    f32x16 acc1, acc2;
    #pragma unroll
    for (int r = 0; r < 16; ++r) { acc1[r] = 0.0f; acc2[r] = 0.0f; }

    // --- A staging role: wave w owns (h_s = w>>2, s_s = (w>>1)&1, j4 = w&1) ---
    const int h_s = w >> 2, s_s = (w >> 1) & 1, j4 = w & 1;
    const float* aSrc = x + (size_t)(row0 + (l & 31)) * DDIM
                          + h_s * 1024 + s_s * 16 + (l >> 5) * 8 + j4 * 4;
    auto loadA = [&](int t) -> float4 {
        return *(const float4*)(aSrc + (size_t)t * KI);
    };
    auto cvtWrite = [&](float4 xv, int buf) {   // buf is compile-time static
        float xs[4] = {xv.x, xv.y, xv.z, xv.w};
        f16x4 hi, lo;
        #pragma unroll
        for (int j = 0; j < 4; ++j) {
            f16 hh   = (f16)xs[j];
            float hf = (float)hh;
            hi[j] = hh;
            lo[j] = (f16)((xs[j] - hf) * 64.0f);
        }
        *(f16x4*)(smem + a_off(buf, h_s, s_s, 0) + l * 16 + j4 * 8) = hi;
        *(f16x4*)(smem + a_off(buf, h_s, s_s, 1) + l * 16 + j4 * 8) = lo;
    };

    // --- B: wave-private, global->reg. Slice S = h*64 + t*2 + s ---
    const f16* bBase = wfrag + (size_t)f * 1024 + l * 8;
#define LOADB(t, H0, L0, H1, L1) do {                                       \
        const f16* _p = bBase + (size_t)(h * 64 + (t) * 2) * 4096;          \
        H0 = *(const f16x8*)_p;          L0 = *(const f16x8*)(_p + 512);    \
        H1 = *(const f16x8*)(_p + 4096); L1 = *(const f16x8*)(_p + 4608);   \
    } while (0)

    auto compute = [&](int buf, f16x8 Bh0, f16x8 Bl0, f16x8 Bh1, f16x8 Bl1) {
        #pragma unroll
        for (int s = 0; s < 2; ++s) {
            f16x8 Ah = *(const f16x8*)(smem + a_off(buf, h, s, 0) + l * 16);
            f16x8 Al = *(const f16x8*)(smem + a_off(buf, h, s, 1) + l * 16);
            f16x8 Bh = s ? Bh1 : Bh0;
            f16x8 Bl = s ? Bl1 : Bl0;
            acc1 = __builtin_amdgcn_mfma_f32_32x32x16_f16(Ah, Bh, acc1, 0, 0, 0);
            acc2 = __builtin_amdgcn_mfma_f32_32x32x16_f16(Ah, Bl, acc2, 0, 0, 0);
            acc2 = __builtin_amdgcn_mfma_f32_32x32x16_f16(Al, Bh, acc2, 0, 0, 0);
        }
    };

    float4 a0, a1, a2, a3;
    f16x8 b0h0, b0l0, b0h1, b0l1;   // B set 0 (even segs)
    f16x8 b1h0, b1l0, b1h1, b1l1;   // B set 1 (odd segs)

    // -------- prologue: A(0..3) regs, B(0),B(1) regs, bufs 0,1 written --------
    a0 = loadA(0); a1 = loadA(1); a2 = loadA(2); a3 = loadA(3);
    LOADB(0, b0h0, b0l0, b0h1, b0l1);
    LOADB(1, b1h0, b1l0, b1h1, b1l1);
    cvtWrite(a0, 0);
    cvtWrite(a1, 1);
    __syncthreads();

    // -------- steady loop: 7 trips x 4 segs, ALL bodies branch-free --------
    // max indices: loadA(tb+7)=31, LOADB(tb+5)=29 -- always valid for tb<=24
    for (int tb = 0; tb <= 24; tb += 4) {
        // seg tb+0: buf0, Bset0
        compute(0, b0h0, b0l0, b0h1, b0l1);
        a0 = loadA(tb + 4);
        LOADB(tb + 2, b0h0, b0l0, b0h1, b0l1);
        cvtWrite(a2, 2);                       // seg tb+2 -> buf2
        __syncthreads();
        // seg tb+1: buf1, Bset1
        compute(1, b1h0, b1l0, b1h1, b1l1);
        a1 = loadA(tb + 5);
        LOADB(tb + 3, b1h0, b1l0, b1h1, b1l1);
        cvtWrite(a3, 3);                       // seg tb+3 -> buf3
        __syncthreads();
        // seg tb+2: buf2, Bset0
        compute(2, b0h0, b0l0, b0h1, b0l1);
        a2 = loadA(tb + 6);
        LOADB(tb + 4, b0h0, b0l0, b0h1, b0l1);
        cvtWrite(a0, 0);                       // seg tb+4 -> buf0
        __syncthreads();
        // seg tb+3: buf3, Bset1
        compute(3, b1h0, b1l0, b1h1, b1l1);
        a3 = loadA(tb + 7);
        LOADB(tb + 5, b1h0, b1l0, b1h1, b1l1);
        cvtWrite(a1, 1);                       // seg tb+5 -> buf1
        __syncthreads();
    }
    // -------- peeled tail: segs 28..31 --------
    // entering: a2=A(30), a3=A(31); sets have B(28),B(29); bufs 0,1 = segs 28,29
    // seg 28: buf0, Bset0
    compute(0, b0h0, b0l0, b0h1, b0l1);
    LOADB(30, b0h0, b0l0, b0h1, b0l1);
    cvtWrite(a2, 2);                           // seg 30 -> buf2
    __syncthreads();
    // seg 29: buf1, Bset1
    compute(1, b1h0, b1l0, b1h1, b1l1);
    LOADB(31, b1h0, b1l0, b1h1, b1l1);
    cvtWrite(a3, 3);                           // seg 31 -> buf3
    __syncthreads();
    // seg 30: buf2, Bset0
    compute(2, b0h0, b0l0, b0h1, b0l1);
    __syncthreads();
    // seg 31: buf3, Bset1
    compute(3, b1h0, b1l0, b1h1, b1l1);
    __syncthreads();
#undef LOADB

    // ---- merge K-halves: h=1 waves write partial, h=0 adds ----
    float* mg = (float*)(smem + 32768);    // [32][128]
    if (h == 1) {
        #pragma unroll
        for (int r = 0; r < 16; ++r) {
            float cv = fmaf(acc2[r], 0.015625f, acc1[r]);
            int row = (r & 3) + 8 * (r >> 2) + 4 * (l >> 5);
            int col = f * 32 + (l & 31);
            mg[row * 128 + col] = cv;
        }
    }
    __syncthreads();

    float* lgf = (float*)smem;             // [32][132]
    if (h == 0) {
        #pragma unroll
        for (int r = 0; r < 16; ++r) {
            float cv = fmaf(acc2[r], 0.015625f, acc1[r]);
            int row = (r & 3) + 8 * (r >> 2) + 4 * (l >> 5);
            int col = f * 32 + (l & 31);
            lgf[row * 132 + col] = cv + mg[row * 128 + col];
        }
    }
    __syncthreads();

    // ---- phase1: noise injection; 512 thr = 32 rows x 16 float4-chunks ----
    {
        const int pr = tid & 31;           // row
        const int c4 = tid >> 5;           // float4 chunk 0..15
        const int n1 = row0 + pr;
        float4 G  = *(const float4*)(lgf + pr * 132 + c4 * 4);
        float4 NL = *(const float4*)(lgf + pr * 132 + 64 + c4 * 4);
        float4 NZ = *(const float4*)(noise + (size_t)n1 * NE + c4 * 4);
        G.x += NZ.x * softplus_f(NL.x) * NSCALE;
        G.y += NZ.y * softplus_f(NL.y) * NSCALE;
        G.z += NZ.z * softplus_f(NL.z) * NSCALE;
        G.w += NZ.w * softplus_f(NL.w) * NSCALE;
        *(float4*)(lgf + pr * 132 + c4 * 4) = G;
        *(float4*)(out_logits + (size_t)n1 * NE + c4 * 4) = G;
    }
    __syncthreads();

    // ---- phase2: per-row top-2 + softmax; waves 0..3, 8 lanes/row ----
    if (w < 4) {
        const int g2   = l >> 3;           // row within wave's 8-row group
        const int c    = l & 7;            // expert chunk of 8
        const int row2 = w * 8 + g2;
        const int n2   = row0 + row2;

        float mv[8];
        {
            const float4* mr = (const float4*)(lgf + row2 * 132 + c * 8);
            float4 m0 = mr[0], m1 = mr[1];
            mv[0]=m0.x; mv[1]=m0.y; mv[2]=m0.z; mv[3]=m0.w;
            mv[4]=m1.x; mv[5]=m1.y; mv[6]=m1.z; mv[7]=m1.w;
        }
        float v0 = -INFINITY, v1 = -INFINITY;
        int i0 = 0, i1 = 0;
        #pragma unroll
        for (int j = 0; j < 8; ++j) {
            float v = mv[j]; int e = c * 8 + j;
            if (v > v0) { v1 = v0; i1 = i0; v0 = v; i0 = e; }
            else if (v > v1) { v1 = v; i1 = e; }
        }
        #pragma unroll
        for (int m = 1; m <= 4; m <<= 1) {
            float ov0 = __shfl_xor(v0, m), ov1 = __shfl_xor(v1, m);
            int   oi0 = __shfl_xor(i0, m), oi1 = __shfl_xor(i1, m);
            if (ov0 > v0) {
                bool keep = (v0 > ov1);
                v1 = keep ? v0 : ov1; i1 = keep ? i0 : oi1;
                v0 = ov0; i0 = oi0;
            } else if (ov0 > v1) {
                v1 = ov0; i1 = oi0;
            }
        }
        const int srcl = l & 56;
        v0 = __shfl(v0, srcl); i0 = __shfl(i0, srcl);
        v1 = __shfl(v1, srcl); i1 = __shfl(i1, srcl);

        float se = 0.0f;
        #pragma unroll
        for (int j = 0; j < 8; ++j) se += expf(mv[j] - v0);
        se += __shfl_xor(se, 1); se += __shfl_xor(se, 2); se += __shfl_xor(se, 4);
        float inv_se = 1.0f / se;

        float t  = expf(v1 - v0);
        float w0 = 1.0f / (1.0f + t);
        float w1 = t * w0;

        float pr[8], wt[8];
        #pragma unroll
        for (int j = 0; j < 8; ++j) {
            int e = c * 8 + j;
            pr[j] = expf(mv[j] - v0) * inv_se;
            wt[j] = (e == i0) ? w0 : ((e == i1) ? w1 : 0.0f);
        }
        *(float4*)(out_probs + (size_t)n2 * NE + c * 8)     = make_float4(pr[0], pr[1], pr[2], pr[3]);
        *(float4*)(out_probs + (size_t)n2 * NE + c * 8 + 4) = make_float4(pr[4], pr[5], pr[6], pr[7]);
        *(float4*)(out_w + (size_t)n2 * NE + c * 8)         = make_float4(wt[0], wt[1], wt[2], wt[3]);
        *(float4*)(out_w + (size_t)n2 * NE + c * 8 + 4)     = make_float4(wt[4], wt[5], wt[6], wt[7]);
        if (c == 0) {
            *(float2*)(out_idx + (size_t)n2 * 2) = make_float2((float)i0, (float)i1);
        }
    }
}

extern "C" void kernel_launch(void* const* d_in, const int* in_sizes, int n_in,
                              void* d_out, int out_size, void* d_ws, size_t ws_size,
                              hipStream_t stream) {
    (void)in_sizes; (void)n_in; (void)ws_size; (void)out_size;
    const float* x     = (const float*)d_in[0];
    const float* Wg    = (const float*)d_in[1];
    const float* Wn    = (const float*)d_in[2];
    const float* noise = (const float*)d_in[3];
    float* out        = (float*)d_out;
    float* out_w      = out;
    float* out_idx    = out + (size_t)NROWS * NE;
    float* out_logits = out_idx + (size_t)NROWS * 2;
    float* out_probs  = out_logits + (size_t)NROWS * NE;
    f16* wfrag = (f16*)d_ws;   // 1 MB

    wprep_kernel<<<128, 256, 0, stream>>>(Wg, Wn, wfrag);
    gemm_gating<<<NROWS / BM, 512, 0, stream>>>(
        x, wfrag, noise, out_w, out_idx, out_logits, out_probs);
}